// Round 6
// baseline (565.719 us; speedup 1.0000x reference)
//
#include <hip/hip_runtime.h>
#include <hip/hip_bf16.h>

#define HWN    1024
#define CCH    512
#define NBATCH 16
#define NGROUP 32
#define EPSV   1e-5f

using bf16 = __hip_bfloat16;
typedef __attribute__((ext_vector_type(4))) float f32x4;
typedef __attribute__((ext_vector_type(8))) short s16x8;

// Runtime-dtyped element access: c==1 -> fp32, c==0 -> bf16 storage.
__device__ __forceinline__ float ldv(const void* p, long i, int c) {
    return c ? ((const float*)p)[i] : __bfloat162float(((const bf16*)p)[i]);
}
__device__ __forceinline__ void stv(void* p, long i, int c, float v) {
    if (c) ((float*)p)[i] = v;
    else   ((bf16*)p)[i]  = __float2bfloat16(v);
}
__device__ __forceinline__ float b2f(unsigned short h) {
    union { float f; unsigned u; } c; c.u = ((unsigned)h) << 16; return c.f;
}
__device__ __forceinline__ unsigned short f2b(float v) {
    bf16 b = __float2bfloat16(v);
    return *(unsigned short*)&b;
}

// ---------------------------------------------------------------------------
// Storage dtype detector (proven in R3). flag=1 => fp32 storage.
// ---------------------------------------------------------------------------
__global__ __launch_bounds__(256) void detect_kernel(const void* __restrict__ x,
                                                     int* __restrict__ flag)
{
    const int tid = threadIdx.x;
    const unsigned short* h = (const unsigned short*)x;
    int ok = 0;
    for (int i = tid; i < 4096; i += 256) {
        int e = (h[2 * i] >> 7) & 0xFF;
        if (e >= 100 && e <= 135) ok++;
    }
    __shared__ int red[256];
    red[tid] = ok; __syncthreads();
    for (int off = 128; off > 0; off >>= 1) {
        if (tid < off) red[tid] += red[tid + off];
        __syncthreads();
    }
    if (tid == 0) flag[0] = (red[0] < 2458) ? 1 : 0;
}

// ---------------------------------------------------------------------------
// GroupNorm stats: one block per (batch, group) -> (mean, rstd).
// ---------------------------------------------------------------------------
__global__ __launch_bounds__(256) void gn_stats_kernel(const void* __restrict__ x,
                                                       const int* __restrict__ flag,
                                                       float2* __restrict__ stats)
{
    const int f = flag[0];
    const int b = blockIdx.x >> 5, g = blockIdx.x & 31;
    const long base = ((long)b * CCH + (long)g * (CCH / NGROUP)) * HWN;
    const int tid = threadIdx.x;
    const int n = (CCH / NGROUP) * HWN;       // 16384
    float s = 0.f, ss = 0.f;
    for (int i = tid; i < n; i += 256) {
        float v = ldv(x, base + i, f);
        s += v; ss += v * v;
    }
    __shared__ float r1[256], r2[256];
    r1[tid] = s; r2[tid] = ss; __syncthreads();
    for (int off = 128; off > 0; off >>= 1) {
        if (tid < off) { r1[tid] += r1[tid + off]; r2[tid] += r2[tid + off]; }
        __syncthreads();
    }
    if (tid == 0) {
        float mean = r1[0] / n;
        float var  = r2[0] / n - mean * mean;
        stats[blockIdx.x] = make_float2(mean, rsqrtf(var + EPSV));
    }
}

// ---------------------------------------------------------------------------
// Weight/bias prep: Wqk = [Wq;Wk] bf16 [1024][512]; Wv,Wo bf16; biases f32.
// ---------------------------------------------------------------------------
__global__ __launch_bounds__(256)
void prep_kernel(const void* __restrict__ Wq, const void* __restrict__ Wk,
                 const void* __restrict__ Wv, const void* __restrict__ Wo,
                 const void* __restrict__ bq, const void* __restrict__ bk,
                 const void* __restrict__ bv, const void* __restrict__ bo,
                 const int* __restrict__ flag,
                 bf16* __restrict__ Wqk, bf16* __restrict__ Wvb, bf16* __restrict__ Wob,
                 float* __restrict__ bQK, float* __restrict__ bV, float* __restrict__ bO)
{
    const int f = flag[0];
    const int idx = blockIdx.x * 256 + threadIdx.x;
    if (idx < 524288) {
        const int r = idx >> 9, c = idx & 511;
        float v = (r < 512) ? ldv(Wq, (long)r * 512 + c, f)
                            : ldv(Wk, (long)(r - 512) * 512 + c, f);
        Wqk[idx] = __float2bfloat16(v);
    } else if (idx < 786432) {
        Wvb[idx - 524288] = __float2bfloat16(ldv(Wv, idx - 524288, f));
    } else if (idx < 1048576) {
        Wob[idx - 786432] = __float2bfloat16(ldv(Wo, idx - 786432, f));
    } else {
        const int j = idx - 1048576;
        if      (j < 512)  bQK[j]        = ldv(bq, j, f);
        else if (j < 1024) bQK[j]        = ldv(bk, j - 512, f);
        else if (j < 1536) bV[j - 1024]  = ldv(bv, j - 1024, f);
        else if (j < 2048) bO[j - 1536]  = ldv(bo, j - 1536, f);
    }
}

// ---------------------------------------------------------------------------
// GN+SiLU with transpose: x [c][i] (flag dtype) -> xn' [i][c] bf16.
// ---------------------------------------------------------------------------
__global__ __launch_bounds__(256)
void gn_apply_kernel(const void* __restrict__ x, const int* __restrict__ flag,
                     const float2* __restrict__ stats,
                     const void* __restrict__ gamma, const void* __restrict__ beta,
                     bf16* __restrict__ xn, int zb)
{
    const int f = flag[0];
    __shared__ float t[64][65];
    const int bz = blockIdx.z;
    const int bx = zb + bz;
    const int i0 = blockIdx.x * 64;
    const int c0 = blockIdx.y * 64;
    const int tid = threadIdx.x;
    const int il = tid & 63;
    const int hq = tid >> 6;              // 0..3
    #pragma unroll
    for (int r = 0; r < 16; ++r) {
        const int cl = r * 4 + hq;
        const int c = c0 + cl;
        const float2 st = stats[bx * NGROUP + (c >> 4)];
        const float ga = ldv(gamma, c, f), be = ldv(beta, c, f);
        float v = ldv(x, (long)bx * CCH * HWN + (long)c * HWN + i0 + il, f);
        v = (v - st.x) * st.y * ga + be;
        t[cl][il] = v / (1.f + __expf(-v));     // SiLU
    }
    __syncthreads();
    #pragma unroll
    for (int r = 0; r < 16; ++r) {
        const int ii = r * 4 + hq;
        xn[(long)bz * CCH * HWN + (long)(i0 + ii) * CCH + c0 + il] =
            __float2bfloat16(t[il][ii]);
    }
}

// ---------------------------------------------------------------------------
// MFMA TN GEMM: C[m][n] = alpha * sum_k A[m][k] * B[n][k]  (+rowBias[m]
// +colBias[n]) (+resid, FINAL). 128x128 tile, BK=32, 4 waves, 16x16x32 bf16.
// Staging: 2-tile-deep global->VGPR prefetch + ds_write (NOT global_load_lds:
// register loads need no vmcnt drain at barriers, so loads get ~2 iterations
// of latency tolerance). LDS rows padded to 40 elems (80 B = 5x16B): all
// ds_write_b128 / ds_read_b128 phase-uniform -> conflict-free.
// ---------------------------------------------------------------------------
#define LSTR 40    // LDS row stride in elements

template<bool FINAL>
__global__ __launch_bounds__(256)
void mfma_gemm(const bf16* __restrict__ A, const bf16* __restrict__ B,
               void* __restrict__ C, int K,
               int lda, int ldb, int ldc,
               long sA, long sB, long sC, int z0,
               const float* __restrict__ rowBias, const float* __restrict__ colBias,
               float alpha, const void* __restrict__ resid, long sR,
               const int* __restrict__ flag)
{
    __shared__ bf16 lA[2][128 * LSTR];
    __shared__ bf16 lB[2][128 * LSTR];

    const int tid = threadIdx.x;
    const int w   = tid >> 6;         // wave 0..3
    const int l   = tid & 63;
    const int ln  = l & 15;
    const int qd  = l >> 4;           // 0..3
    const int wm  = (w >> 1) * 64;
    const int wn  = (w & 1) * 64;
    const int zA  = z0 + blockIdx.z;

    const bf16* Ab = A + (long)zA * sA;
    const bf16* Bb = B + (long)zA * sB;
    const int m0 = blockIdx.y * 128;
    const int n0 = blockIdx.x * 128;

    // staging geometry: lane -> local row l>>2 (0..15), 16B col-seg l&3
    const int sr  = l >> 2;
    const int scg = (l & 3) * 8;                   // element col offset
    const bf16* gA0 = Ab + (long)(m0 + w * 16 + sr) * lda + scg;
    const bf16* gA1 = gA0 + (long)64 * lda;
    const bf16* gB0 = Bb + (long)(n0 + w * 16 + sr) * ldb + scg;
    const bf16* gB1 = gB0 + (long)64 * ldb;
    const int dA0 = (w * 16 + sr) * LSTR + scg;    // LDS element index
    const int dA1 = dA0 + 64 * LSTR;

    f32x4 acc[4][4];
    #pragma unroll
    for (int i = 0; i < 4; ++i)
        #pragma unroll
        for (int j = 0; j < 4; ++j)
            acc[i][j] = (f32x4){0.f, 0.f, 0.f, 0.f};

    const int NK = K >> 5;
    float4 rA0[2], rA1[2], rB0[2], rB1[2];         // 2-tile prefetch slots

    // prologue: load tile0 -> slot0, tile1 -> slot1, write tile0 to buf0
    rA0[0] = *(const float4*)(gA0);  rA1[0] = *(const float4*)(gA1);
    rB0[0] = *(const float4*)(gB0);  rB1[0] = *(const float4*)(gB1);
    if (NK > 1) {
        rA0[1] = *(const float4*)(gA0 + 32);  rA1[1] = *(const float4*)(gA1 + 32);
        rB0[1] = *(const float4*)(gB0 + 32);  rB1[1] = *(const float4*)(gB1 + 32);
    }
    *(float4*)&lA[0][dA0] = rA0[0];  *(float4*)&lA[0][dA1] = rA1[0];
    *(float4*)&lB[0][dA0] = rB0[0];  *(float4*)&lB[0][dA1] = rB1[0];
    __syncthreads();

    for (int t = 0; t < NK; ++t) {
        const int p = t & 1;
        if (t + 2 < NK) {                          // prefetch tile t+2 -> slot p
            const int kk = (t + 2) << 5;
            rA0[p] = *(const float4*)(gA0 + kk);
            rA1[p] = *(const float4*)(gA1 + kk);
            rB0[p] = *(const float4*)(gB0 + kk);
            rB1[p] = *(const float4*)(gB1 + kk);
        }
        s16x8 af[4], bfr[4];                       // frags of tile t from buf p
        #pragma unroll
        for (int i = 0; i < 4; ++i)
            af[i] = *(const s16x8*)&lA[p][(wm + i * 16 + ln) * LSTR + qd * 8];
        #pragma unroll
        for (int j = 0; j < 4; ++j)
            bfr[j] = *(const s16x8*)&lB[p][(wn + j * 16 + ln) * LSTR + qd * 8];
        if (t + 1 < NK) {                          // stage tile t+1 -> buf p^1
            *(float4*)&lA[p ^ 1][dA0] = rA0[p ^ 1];
            *(float4*)&lA[p ^ 1][dA1] = rA1[p ^ 1];
            *(float4*)&lB[p ^ 1][dA0] = rB0[p ^ 1];
            *(float4*)&lB[p ^ 1][dA1] = rB1[p ^ 1];
        }
        #pragma unroll
        for (int i = 0; i < 4; ++i)
            #pragma unroll
            for (int j = 0; j < 4; ++j)
                acc[i][j] = __builtin_amdgcn_mfma_f32_16x16x32_bf16(
                    af[i], bfr[j], acc[i][j], 0, 0, 0);
        __syncthreads();
    }

    // epilogue: C/D layout col = lane&15, row = qd*4 + reg  [m89]
    const int f = (FINAL && flag) ? flag[0] : 0;
    #pragma unroll
    for (int i = 0; i < 4; ++i) {
        #pragma unroll
        for (int j = 0; j < 4; ++j) {
            const int mBase = m0 + wm + i * 16 + qd * 4;
            const int n = n0 + wn + j * 16 + ln;
            const float cb = colBias ? colBias[n] : 0.f;
            #pragma unroll
            for (int r = 0; r < 4; ++r) {
                const int m = mBase + r;
                float v = alpha * acc[i][j][r] + cb;
                if (rowBias) v += rowBias[m];
                const long idx = (long)zA * sC + (long)m * ldc + n;
                if (FINAL) {
                    if (resid) v += ldv(resid, (long)zA * sR + (long)m * ldc + n, f);
                    stv(C, idx, f, v);
                } else {
                    ((bf16*)C)[idx] = __float2bfloat16(v);
                }
            }
        }
    }
}

// ---------------------------------------------------------------------------
// Row softmax over 1024 bf16, in place. One block per row, ushort4 vectorized.
// ---------------------------------------------------------------------------
__global__ __launch_bounds__(256)
void softmax_kernel(bf16* __restrict__ S)
{
    ushort4* p = (ushort4*)(S + (long)blockIdx.x * HWN);
    const int tid = threadIdx.x;
    ushort4 u = p[tid];
    float v[4] = { b2f(u.x), b2f(u.y), b2f(u.z), b2f(u.w) };
    float mx = fmaxf(fmaxf(v[0], v[1]), fmaxf(v[2], v[3]));

    __shared__ float red[256];
    red[tid] = mx; __syncthreads();
    for (int off = 128; off > 0; off >>= 1) {
        if (tid < off) red[tid] = fmaxf(red[tid], red[tid + off]);
        __syncthreads();
    }
    mx = red[0]; __syncthreads();
    float s = 0.f;
    #pragma unroll
    for (int i = 0; i < 4; ++i) { v[i] = __expf(v[i] - mx); s += v[i]; }
    red[tid] = s; __syncthreads();
    for (int off = 128; off > 0; off >>= 1) {
        if (tid < off) red[tid] += red[tid + off];
        __syncthreads();
    }
    const float inv = 1.f / red[0];
    u.x = f2b(v[0] * inv); u.y = f2b(v[1] * inv);
    u.z = f2b(v[2] * inv); u.w = f2b(v[3] * inv);
    p[tid] = u;
}

// ---------------------------------------------------------------------------
extern "C" void kernel_launch(void* const* d_in, const int* in_sizes, int n_in,
                              void* d_out, int out_size, void* d_ws, size_t ws_size,
                              hipStream_t stream)
{
    // input order (insertion per docs; alphabetical fallback) — proven in R3
    const long NX = (long)NBATCH * CCH * HWN;
    int ix, iWq, ibq, iWk, ibk, iWv, ibv, iWo, ibo, iga, ibe;
    if (in_sizes[0] == NX) {
        ix = 0; iWq = 1; ibq = 2; iWk = 3; ibk = 4; iWv = 5; ibv = 6;
        iWo = 7; ibo = 8; iga = 9; ibe = 10;
    } else {
        iWk = 0; iWo = 1; iWq = 2; iWv = 3; ibe = 4; ibk = 5; ibo = 6;
        ibq = 7; ibv = 8; iga = 9; ix = 10;
    }
    const void* x     = d_in[ix];
    const void* Wq    = d_in[iWq];
    const void* bq    = d_in[ibq];
    const void* Wk    = d_in[iWk];
    const void* bk    = d_in[ibk];
    const void* Wv    = d_in[iWv];
    const void* bv    = d_in[ibv];
    const void* Wo    = d_in[iWo];
    const void* bo    = d_in[ibo];
    const void* gamma = d_in[iga];
    const void* beta  = d_in[ibe];

    const long CHW = (long)CCH * HWN;      // 524288
    const long NN  = (long)HWN * HWN;      // 1048576
    const size_t MB = 1ull << 20;
    char* ws = (char*)d_ws;

    bf16*   Wqk   = (bf16*)ws;                         // 1 MB
    bf16*   Wvb   = (bf16*)(ws + MB);                  // 0.5 MB
    bf16*   Wob   = (bf16*)(ws + MB + MB / 2);         // 0.5 MB
    float*  bQK   = (float*)(ws + 2 * MB);
    float*  bV    = (float*)(ws + 2 * MB + 4096);
    float*  bO    = (float*)(ws + 2 * MB + 6144);
    float2* stats = (float2*)(ws + 2 * MB + 8192);
    int*    flag  = (int*)(ws + 2 * MB + 12288);

    dim3 blk(256);
    const float scale = 0.044194173824159216f;   // 512^-0.5
    const float* FNUL = nullptr;
    const void*  VNUL = nullptr;

    detect_kernel<<<dim3(1), blk, 0, stream>>>(x, flag);
    gn_stats_kernel<<<dim3(NBATCH * NGROUP), blk, 0, stream>>>(x, flag, stats);
    prep_kernel<<<dim3(4104), blk, 0, stream>>>(Wq, Wk, Wv, Wo, bq, bk, bv, bo,
                                                flag, Wqk, Wvb, Wob, bQK, bV, bO);

    const int tier = (ws_size >= 100 * MB) ? 1 : (ws_size >= 70 * MB) ? 2 : 3;

    if (tier <= 2) {
        bf16* xn = (bf16*)(ws + 3 * MB);      // 16 MB [i][c] per batch
        bf16* V  = (bf16*)(ws + 19 * MB);     // 16 MB [c][j] per batch
        bf16* QK = (bf16*)(ws + 35 * MB);     // 32 MB [i][1024] per batch
        bf16* S  = (bf16*)(ws + 67 * MB);     // 32 MB (tier1) / 2 MB (tier2)
        bf16* O  = xn;                        // overlay: xn dead after V GEMM

        gn_apply_kernel<<<dim3(16, 8, NBATCH), blk, 0, stream>>>(
            x, flag, stats, gamma, beta, xn, 0);

        // QK' = xn' @ [Wq;Wk]^T + bias  (M=1024,N=1024,K=512)
        mfma_gemm<false><<<dim3(8, 8, NBATCH), blk, 0, stream>>>(
            xn, Wqk, QK, 512, 512, 512, 1024, CHW, 0L, NN, 0,
            FNUL, bQK, 1.f, VNUL, 0L, nullptr);
        // V[c][j] = Wv @ gn(x): A=Wv, B=xn'  (M=512,N=1024,K=512)
        mfma_gemm<false><<<dim3(8, 4, NBATCH), blk, 0, stream>>>(
            Wvb, xn, V, 512, 512, 512, 1024, 0L, CHW, CHW, 0,
            bV, FNUL, 1.f, VNUL, 0L, nullptr);

        if (tier == 1) {
            // S = scale * Q' K'^T  (M=N=1024,K=512)
            mfma_gemm<false><<<dim3(8, 8, NBATCH), blk, 0, stream>>>(
                QK, QK + 512, S, 512, 1024, 1024, 1024, NN, NN, NN, 0,
                FNUL, FNUL, scale, VNUL, 0L, nullptr);
            softmax_kernel<<<dim3(NBATCH * HWN), blk, 0, stream>>>(S);
            // O' = P @ V^T  (M=1024,N=512,K=1024)
            mfma_gemm<false><<<dim3(4, 8, NBATCH), blk, 0, stream>>>(
                S, V, O, 1024, 1024, 1024, 512, NN, CHW, CHW, 0,
                FNUL, FNUL, 1.f, VNUL, 0L, nullptr);
        } else {
            for (int b = 0; b < NBATCH; ++b) {
                mfma_gemm<false><<<dim3(8, 8, 1), blk, 0, stream>>>(
                    QK, QK + 512, S, 512, 1024, 1024, 1024, NN, NN, 0L, b,
                    FNUL, FNUL, scale, VNUL, 0L, nullptr);
                softmax_kernel<<<dim3(HWN), blk, 0, stream>>>(S);
                mfma_gemm<false><<<dim3(4, 8, 1), blk, 0, stream>>>(
                    S, V, O, 1024, 1024, 1024, 512, 0L, CHW, CHW, b,
                    FNUL, FNUL, 1.f, VNUL, 0L, nullptr);
            }
        }
        // out = Wo @ O'^T + bo + x  (M=512,N=1024,K=512), flag-dtype store
        mfma_gemm<true><<<dim3(8, 4, NBATCH), blk, 0, stream>>>(
            Wob, O, d_out, 512, 512, 512, 1024, 0L, CHW, CHW, 0,
            bO, FNUL, 1.f, x, CHW, flag);
    } else {
        // tier 3: fully per-batch (ws >= 9 MB)
        bf16* xn = (bf16*)(ws + 3 * MB);      // 1 MB
        bf16* V  = (bf16*)(ws + 4 * MB);      // 1 MB
        bf16* QK = (bf16*)(ws + 5 * MB);      // 2 MB
        bf16* S  = (bf16*)(ws + 7 * MB);      // 2 MB
        bf16* O  = xn;
        for (int b = 0; b < NBATCH; ++b) {
            gn_apply_kernel<<<dim3(16, 8, 1), blk, 0, stream>>>(
                x, flag, stats, gamma, beta, xn, b);
            mfma_gemm<false><<<dim3(8, 8, 1), blk, 0, stream>>>(
                xn, Wqk, QK, 512, 512, 512, 1024, 0L, 0L, 0L, 0,
                FNUL, bQK, 1.f, VNUL, 0L, nullptr);
            mfma_gemm<false><<<dim3(8, 4, 1), blk, 0, stream>>>(
                Wvb, xn, V, 512, 512, 512, 1024, 0L, 0L, 0L, 0,
                bV, FNUL, 1.f, VNUL, 0L, nullptr);
            mfma_gemm<false><<<dim3(8, 8, 1), blk, 0, stream>>>(
                QK, QK + 512, S, 512, 1024, 1024, 1024, 0L, 0L, 0L, 0,
                FNUL, FNUL, scale, VNUL, 0L, nullptr);
            softmax_kernel<<<dim3(HWN), blk, 0, stream>>>(S);
            mfma_gemm<false><<<dim3(4, 8, 1), blk, 0, stream>>>(
                S, V, O, 1024, 1024, 1024, 512, 0L, 0L, 0L, 0,
                FNUL, FNUL, 1.f, VNUL, 0L, nullptr);
            mfma_gemm<true><<<dim3(8, 4, 1), blk, 0, stream>>>(
                Wob, O, d_out, 512, 512, 512, 1024, 0L, 0L, CHW, b,
                bO, FNUL, 1.f, x, CHW, flag);
        }
    }
}

// Round 7
// 454.491 us; speedup vs baseline: 1.2447x; 1.2447x over previous
//
#include <hip/hip_runtime.h>
#include <hip/hip_bf16.h>

#define HWN    1024
#define CCH    512
#define NBATCH 16
#define NGROUP 32
#define EPSV   1e-5f

using bf16 = __hip_bfloat16;
typedef __attribute__((ext_vector_type(4))) float f32x4;
typedef __attribute__((ext_vector_type(8))) short s16x8;

// Runtime-dtyped element access: c==1 -> fp32, c==0 -> bf16 storage.
__device__ __forceinline__ float ldv(const void* p, long i, int c) {
    return c ? ((const float*)p)[i] : __bfloat162float(((const bf16*)p)[i]);
}
__device__ __forceinline__ void stv(void* p, long i, int c, float v) {
    if (c) ((float*)p)[i] = v;
    else   ((bf16*)p)[i]  = __float2bfloat16(v);
}
__device__ __forceinline__ float b2f(unsigned short h) {
    union { float f; unsigned u; } c; c.u = ((unsigned)h) << 16; return c.f;
}
__device__ __forceinline__ unsigned short f2b(float v) {
    bf16 b = __float2bfloat16(v);
    return *(unsigned short*)&b;
}

// ---------------------------------------------------------------------------
// Storage dtype detector (proven in R3). flag=1 => fp32 storage.
// ---------------------------------------------------------------------------
__global__ __launch_bounds__(256) void detect_kernel(const void* __restrict__ x,
                                                     int* __restrict__ flag)
{
    const int tid = threadIdx.x;
    const unsigned short* h = (const unsigned short*)x;
    int ok = 0;
    for (int i = tid; i < 4096; i += 256) {
        int e = (h[2 * i] >> 7) & 0xFF;
        if (e >= 100 && e <= 135) ok++;
    }
    __shared__ int red[256];
    red[tid] = ok; __syncthreads();
    for (int off = 128; off > 0; off >>= 1) {
        if (tid < off) red[tid] += red[tid + off];
        __syncthreads();
    }
    if (tid == 0) flag[0] = (red[0] < 2458) ? 1 : 0;
}

// ---------------------------------------------------------------------------
// GroupNorm stats: one block per (batch, group) -> (mean, rstd).
// ---------------------------------------------------------------------------
__global__ __launch_bounds__(256) void gn_stats_kernel(const void* __restrict__ x,
                                                       const int* __restrict__ flag,
                                                       float2* __restrict__ stats)
{
    const int f = flag[0];
    const int b = blockIdx.x >> 5, g = blockIdx.x & 31;
    const long base = ((long)b * CCH + (long)g * (CCH / NGROUP)) * HWN;
    const int tid = threadIdx.x;
    const int n = (CCH / NGROUP) * HWN;       // 16384
    float s = 0.f, ss = 0.f;
    for (int i = tid; i < n; i += 256) {
        float v = ldv(x, base + i, f);
        s += v; ss += v * v;
    }
    __shared__ float r1[256], r2[256];
    r1[tid] = s; r2[tid] = ss; __syncthreads();
    for (int off = 128; off > 0; off >>= 1) {
        if (tid < off) { r1[tid] += r1[tid + off]; r2[tid] += r2[tid + off]; }
        __syncthreads();
    }
    if (tid == 0) {
        float mean = r1[0] / n;
        float var  = r2[0] / n - mean * mean;
        stats[blockIdx.x] = make_float2(mean, rsqrtf(var + EPSV));
    }
}

// ---------------------------------------------------------------------------
// Weight/bias prep: Wqk = [Wq;Wk] bf16 [1024][512]; Wv,Wo bf16; biases f32.
// ---------------------------------------------------------------------------
__global__ __launch_bounds__(256)
void prep_kernel(const void* __restrict__ Wq, const void* __restrict__ Wk,
                 const void* __restrict__ Wv, const void* __restrict__ Wo,
                 const void* __restrict__ bq, const void* __restrict__ bk,
                 const void* __restrict__ bv, const void* __restrict__ bo,
                 const int* __restrict__ flag,
                 bf16* __restrict__ Wqk, bf16* __restrict__ Wvb, bf16* __restrict__ Wob,
                 float* __restrict__ bQK, float* __restrict__ bV, float* __restrict__ bO)
{
    const int f = flag[0];
    const int idx = blockIdx.x * 256 + threadIdx.x;
    if (idx < 524288) {
        const int r = idx >> 9, c = idx & 511;
        float v = (r < 512) ? ldv(Wq, (long)r * 512 + c, f)
                            : ldv(Wk, (long)(r - 512) * 512 + c, f);
        Wqk[idx] = __float2bfloat16(v);
    } else if (idx < 786432) {
        Wvb[idx - 524288] = __float2bfloat16(ldv(Wv, idx - 524288, f));
    } else if (idx < 1048576) {
        Wob[idx - 786432] = __float2bfloat16(ldv(Wo, idx - 786432, f));
    } else {
        const int j = idx - 1048576;
        if      (j < 512)  bQK[j]        = ldv(bq, j, f);
        else if (j < 1024) bQK[j]        = ldv(bk, j - 512, f);
        else if (j < 1536) bV[j - 1024]  = ldv(bv, j - 1024, f);
        else if (j < 2048) bO[j - 1536]  = ldv(bo, j - 1536, f);
    }
}

// ---------------------------------------------------------------------------
// GN+SiLU with transpose: x [c][i] (flag dtype) -> xn' [i][c] bf16.
// ---------------------------------------------------------------------------
__global__ __launch_bounds__(256)
void gn_apply_kernel(const void* __restrict__ x, const int* __restrict__ flag,
                     const float2* __restrict__ stats,
                     const void* __restrict__ gamma, const void* __restrict__ beta,
                     bf16* __restrict__ xn, int zb)
{
    const int f = flag[0];
    __shared__ float t[64][65];
    const int bz = blockIdx.z;
    const int bx = zb + bz;
    const int i0 = blockIdx.x * 64;
    const int c0 = blockIdx.y * 64;
    const int tid = threadIdx.x;
    const int il = tid & 63;
    const int hq = tid >> 6;              // 0..3
    #pragma unroll
    for (int r = 0; r < 16; ++r) {
        const int cl = r * 4 + hq;
        const int c = c0 + cl;
        const float2 st = stats[bx * NGROUP + (c >> 4)];
        const float ga = ldv(gamma, c, f), be = ldv(beta, c, f);
        float v = ldv(x, (long)bx * CCH * HWN + (long)c * HWN + i0 + il, f);
        v = (v - st.x) * st.y * ga + be;
        t[cl][il] = v / (1.f + __expf(-v));     // SiLU
    }
    __syncthreads();
    #pragma unroll
    for (int r = 0; r < 16; ++r) {
        const int ii = r * 4 + hq;
        xn[(long)bz * CCH * HWN + (long)(i0 + ii) * CCH + c0 + il] =
            __float2bfloat16(t[il][ii]);
    }
}

// ---------------------------------------------------------------------------
// MFMA TN GEMM: C[m][n] = alpha * sum_k A[m][k] * B[n][k]  (+rowBias[m]
// +colBias[n]) (+resid, FINAL). 128x128 tile, BK=32, 4 waves, 16x16x32 bf16.
// Staging: global->VGPR prefetch (NAMED slots, manual unroll-by-2 so no
// dynamic register indexing -> no scratch) + ds_write double-buffer.
// LDS layout (R5-verified conflict-free): stride-32 rows; slot s of row r
// holds global kseg s ^ ((r>>1)&3); frag reads at (qd ^ ((ln>>1)&3))*8.
// ---------------------------------------------------------------------------
template<bool FINAL>
__global__ __launch_bounds__(256)
void mfma_gemm(const bf16* __restrict__ A, const bf16* __restrict__ B,
               void* __restrict__ C, int K,
               int lda, int ldb, int ldc,
               long sA, long sB, long sC, int z0,
               const float* __restrict__ rowBias, const float* __restrict__ colBias,
               float alpha, const void* __restrict__ resid, long sR,
               const int* __restrict__ flag)
{
    __shared__ bf16 lA[2][128 * 32];
    __shared__ bf16 lB[2][128 * 32];

    const int tid = threadIdx.x;
    const int w   = tid >> 6;         // wave 0..3
    const int l   = tid & 63;
    const int ln  = l & 15;
    const int qd  = l >> 4;           // 0..3
    const int wm  = (w >> 1) * 64;
    const int wn  = (w & 1) * 64;
    const int zA  = z0 + blockIdx.z;

    const bf16* Ab = A + (long)zA * sA;
    const bf16* Bb = B + (long)zA * sB;
    const int m0 = blockIdx.y * 128;
    const int n0 = blockIdx.x * 128;

    // staging geometry: lane -> local row l>>2, LDS slot l&3 holding swizzled kseg
    const int sr   = l >> 2;
    const int kswz = ((l & 3) ^ ((sr >> 1) & 3)) * 8;   // global elem col offset
    const bf16* gA0 = Ab + (long)(m0 + w * 16 + sr) * lda + kswz;
    const bf16* gA1 = gA0 + (long)64 * lda;
    const bf16* gB0 = Bb + (long)(n0 + w * 16 + sr) * ldb + kswz;
    const bf16* gB1 = gB0 + (long)64 * ldb;
    const int dst  = (w * 16 + sr) * 32 + (l & 3) * 8;  // LDS elem index
    const int dst1 = dst + 64 * 32;

    // frag read offset: 2-way aliasing only (R5: measured 0 conflicts)
    const int swA = (qd ^ ((ln >> 1) & 3)) * 8;

    f32x4 acc[4][4];
    #pragma unroll
    for (int i = 0; i < 4; ++i)
        #pragma unroll
        for (int j = 0; j < 4; ++j)
            acc[i][j] = (f32x4){0.f, 0.f, 0.f, 0.f};

    const int NK = K >> 5;
    // named prefetch slots (slot0 = even tiles, slot1 = odd tiles)
    float4 sA0a, sA0b, sB0a, sB0b, sA1a, sA1b, sB1a, sB1b;

    // prologue: tile0 -> slot0 -> buf0; tile1 -> slot1 (stays in regs)
    sA0a = *(const float4*)gA0;  sA0b = *(const float4*)gA1;
    sB0a = *(const float4*)gB0;  sB0b = *(const float4*)gB1;
    if (NK > 1) {
        sA1a = *(const float4*)(gA0 + 32);  sA1b = *(const float4*)(gA1 + 32);
        sB1a = *(const float4*)(gB0 + 32);  sB1b = *(const float4*)(gB1 + 32);
    }
    *(float4*)&lA[0][dst] = sA0a;  *(float4*)&lA[0][dst1] = sA0b;
    *(float4*)&lB[0][dst] = sB0a;  *(float4*)&lB[0][dst1] = sB0b;
    __syncthreads();

    for (int t = 0; t < NK; t += 2) {
        // ---- iter A: tile t lives in buf0 ----
        if (t + 2 < NK) {                       // prefetch tile t+2 -> slot0
            const int kk = (t + 2) << 5;
            sA0a = *(const float4*)(gA0 + kk);  sA0b = *(const float4*)(gA1 + kk);
            sB0a = *(const float4*)(gB0 + kk);  sB0b = *(const float4*)(gB1 + kk);
        }
        if (t + 1 < NK) {                       // stage tile t+1 -> buf1
            *(float4*)&lA[1][dst] = sA1a;  *(float4*)&lA[1][dst1] = sA1b;
            *(float4*)&lB[1][dst] = sB1a;  *(float4*)&lB[1][dst1] = sB1b;
        }
        {
            s16x8 af[4], bfr[4];
            #pragma unroll
            for (int i = 0; i < 4; ++i)
                af[i] = *(const s16x8*)&lA[0][(wm + i * 16 + ln) * 32 + swA];
            #pragma unroll
            for (int j = 0; j < 4; ++j)
                bfr[j] = *(const s16x8*)&lB[0][(wn + j * 16 + ln) * 32 + swA];
            #pragma unroll
            for (int i = 0; i < 4; ++i)
                #pragma unroll
                for (int j = 0; j < 4; ++j)
                    acc[i][j] = __builtin_amdgcn_mfma_f32_16x16x32_bf16(
                        af[i], bfr[j], acc[i][j], 0, 0, 0);
        }
        __syncthreads();
        if (t + 1 >= NK) break;

        // ---- iter B: tile t+1 lives in buf1 ----
        if (t + 3 < NK) {                       // prefetch tile t+3 -> slot1
            const int kk = (t + 3) << 5;
            sA1a = *(const float4*)(gA0 + kk);  sA1b = *(const float4*)(gA1 + kk);
            sB1a = *(const float4*)(gB0 + kk);  sB1b = *(const float4*)(gB1 + kk);
        }
        if (t + 2 < NK) {                       // stage tile t+2 -> buf0
            *(float4*)&lA[0][dst] = sA0a;  *(float4*)&lA[0][dst1] = sA0b;
            *(float4*)&lB[0][dst] = sB0a;  *(float4*)&lB[0][dst1] = sB0b;
        }
        {
            s16x8 af[4], bfr[4];
            #pragma unroll
            for (int i = 0; i < 4; ++i)
                af[i] = *(const s16x8*)&lA[1][(wm + i * 16 + ln) * 32 + swA];
            #pragma unroll
            for (int j = 0; j < 4; ++j)
                bfr[j] = *(const s16x8*)&lB[1][(wn + j * 16 + ln) * 32 + swA];
            #pragma unroll
            for (int i = 0; i < 4; ++i)
                #pragma unroll
                for (int j = 0; j < 4; ++j)
                    acc[i][j] = __builtin_amdgcn_mfma_f32_16x16x32_bf16(
                        af[i], bfr[j], acc[i][j], 0, 0, 0);
        }
        __syncthreads();
    }

    // epilogue: C/D layout col = lane&15, row = qd*4 + reg  [m89]
    const int f = (FINAL && flag) ? flag[0] : 0;
    #pragma unroll
    for (int i = 0; i < 4; ++i) {
        #pragma unroll
        for (int j = 0; j < 4; ++j) {
            const int mBase = m0 + wm + i * 16 + qd * 4;
            const int n = n0 + wn + j * 16 + ln;
            const float cb = colBias ? colBias[n] : 0.f;
            #pragma unroll
            for (int r = 0; r < 4; ++r) {
                const int m = mBase + r;
                float v = alpha * acc[i][j][r] + cb;
                if (rowBias) v += rowBias[m];
                const long idx = (long)zA * sC + (long)m * ldc + n;
                if (FINAL) {
                    if (resid) v += ldv(resid, (long)zA * sR + (long)m * ldc + n, f);
                    stv(C, idx, f, v);
                } else {
                    ((bf16*)C)[idx] = __float2bfloat16(v);
                }
            }
        }
    }
}

// ---------------------------------------------------------------------------
// Row softmax over 1024 bf16, in place. One block per row, ushort4 vectorized.
// ---------------------------------------------------------------------------
__global__ __launch_bounds__(256)
void softmax_kernel(bf16* __restrict__ S)
{
    ushort4* p = (ushort4*)(S + (long)blockIdx.x * HWN);
    const int tid = threadIdx.x;
    ushort4 u = p[tid];
    float v[4] = { b2f(u.x), b2f(u.y), b2f(u.z), b2f(u.w) };
    float mx = fmaxf(fmaxf(v[0], v[1]), fmaxf(v[2], v[3]));

    __shared__ float red[256];
    red[tid] = mx; __syncthreads();
    for (int off = 128; off > 0; off >>= 1) {
        if (tid < off) red[tid] = fmaxf(red[tid], red[tid + off]);
        __syncthreads();
    }
    mx = red[0]; __syncthreads();
    float s = 0.f;
    #pragma unroll
    for (int i = 0; i < 4; ++i) { v[i] = __expf(v[i] - mx); s += v[i]; }
    red[tid] = s; __syncthreads();
    for (int off = 128; off > 0; off >>= 1) {
        if (tid < off) red[tid] += red[tid + off];
        __syncthreads();
    }
    const float inv = 1.f / red[0];
    u.x = f2b(v[0] * inv); u.y = f2b(v[1] * inv);
    u.z = f2b(v[2] * inv); u.w = f2b(v[3] * inv);
    p[tid] = u;
}

// ---------------------------------------------------------------------------
extern "C" void kernel_launch(void* const* d_in, const int* in_sizes, int n_in,
                              void* d_out, int out_size, void* d_ws, size_t ws_size,
                              hipStream_t stream)
{
    // input order (insertion per docs; alphabetical fallback) — proven in R3
    const long NX = (long)NBATCH * CCH * HWN;
    int ix, iWq, ibq, iWk, ibk, iWv, ibv, iWo, ibo, iga, ibe;
    if (in_sizes[0] == NX) {
        ix = 0; iWq = 1; ibq = 2; iWk = 3; ibk = 4; iWv = 5; ibv = 6;
        iWo = 7; ibo = 8; iga = 9; ibe = 10;
    } else {
        iWk = 0; iWo = 1; iWq = 2; iWv = 3; ibe = 4; ibk = 5; ibo = 6;
        ibq = 7; ibv = 8; iga = 9; ix = 10;
    }
    const void* x     = d_in[ix];
    const void* Wq    = d_in[iWq];
    const void* bq    = d_in[ibq];
    const void* Wk    = d_in[iWk];
    const void* bk    = d_in[ibk];
    const void* Wv    = d_in[iWv];
    const void* bv    = d_in[ibv];
    const void* Wo    = d_in[iWo];
    const void* bo    = d_in[ibo];
    const void* gamma = d_in[iga];
    const void* beta  = d_in[ibe];

    const long CHW = (long)CCH * HWN;      // 524288
    const long NN  = (long)HWN * HWN;      // 1048576
    const size_t MB = 1ull << 20;
    char* ws = (char*)d_ws;

    bf16*   Wqk   = (bf16*)ws;                         // 1 MB
    bf16*   Wvb   = (bf16*)(ws + MB);                  // 0.5 MB
    bf16*   Wob   = (bf16*)(ws + MB + MB / 2);         // 0.5 MB
    float*  bQK   = (float*)(ws + 2 * MB);
    float*  bV    = (float*)(ws + 2 * MB + 4096);
    float*  bO    = (float*)(ws + 2 * MB + 6144);
    float2* stats = (float2*)(ws + 2 * MB + 8192);
    int*    flag  = (int*)(ws + 2 * MB + 12288);

    dim3 blk(256);
    const float scale = 0.044194173824159216f;   // 512^-0.5
    const float* FNUL = nullptr;
    const void*  VNUL = nullptr;

    detect_kernel<<<dim3(1), blk, 0, stream>>>(x, flag);
    gn_stats_kernel<<<dim3(NBATCH * NGROUP), blk, 0, stream>>>(x, flag, stats);
    prep_kernel<<<dim3(4104), blk, 0, stream>>>(Wq, Wk, Wv, Wo, bq, bk, bv, bo,
                                                flag, Wqk, Wvb, Wob, bQK, bV, bO);

    const int tier = (ws_size >= 100 * MB) ? 1 : (ws_size >= 70 * MB) ? 2 : 3;

    if (tier <= 2) {
        bf16* xn = (bf16*)(ws + 3 * MB);      // 16 MB [i][c] per batch
        bf16* V  = (bf16*)(ws + 19 * MB);     // 16 MB [c][j] per batch
        bf16* QK = (bf16*)(ws + 35 * MB);     // 32 MB [i][1024] per batch
        bf16* S  = (bf16*)(ws + 67 * MB);     // 32 MB (tier1) / 2 MB (tier2)
        bf16* O  = xn;                        // overlay: xn dead after V GEMM

        gn_apply_kernel<<<dim3(16, 8, NBATCH), blk, 0, stream>>>(
            x, flag, stats, gamma, beta, xn, 0);

        // QK' = xn' @ [Wq;Wk]^T + bias  (M=1024,N=1024,K=512)
        mfma_gemm<false><<<dim3(8, 8, NBATCH), blk, 0, stream>>>(
            xn, Wqk, QK, 512, 512, 512, 1024, CHW, 0L, NN, 0,
            FNUL, bQK, 1.f, VNUL, 0L, nullptr);
        // V[c][j] = Wv @ gn(x): A=Wv, B=xn'  (M=512,N=1024,K=512)
        mfma_gemm<false><<<dim3(8, 4, NBATCH), blk, 0, stream>>>(
            Wvb, xn, V, 512, 512, 512, 1024, 0L, CHW, CHW, 0,
            bV, FNUL, 1.f, VNUL, 0L, nullptr);

        if (tier == 1) {
            // S = scale * Q' K'^T  (M=N=1024,K=512)
            mfma_gemm<false><<<dim3(8, 8, NBATCH), blk, 0, stream>>>(
                QK, QK + 512, S, 512, 1024, 1024, 1024, NN, NN, NN, 0,
                FNUL, FNUL, scale, VNUL, 0L, nullptr);
            softmax_kernel<<<dim3(NBATCH * HWN), blk, 0, stream>>>(S);
            // O' = P @ V^T  (M=1024,N=512,K=1024)
            mfma_gemm<false><<<dim3(4, 8, NBATCH), blk, 0, stream>>>(
                S, V, O, 1024, 1024, 1024, 512, NN, CHW, CHW, 0,
                FNUL, FNUL, 1.f, VNUL, 0L, nullptr);
        } else {
            for (int b = 0; b < NBATCH; ++b) {
                mfma_gemm<false><<<dim3(8, 8, 1), blk, 0, stream>>>(
                    QK, QK + 512, S, 512, 1024, 1024, 1024, NN, NN, 0L, b,
                    FNUL, FNUL, scale, VNUL, 0L, nullptr);
                softmax_kernel<<<dim3(HWN), blk, 0, stream>>>(S);
                mfma_gemm<false><<<dim3(4, 8, 1), blk, 0, stream>>>(
                    S, V, O, 1024, 1024, 1024, 512, 0L, CHW, CHW, b,
                    FNUL, FNUL, 1.f, VNUL, 0L, nullptr);
            }
        }
        // out = Wo @ O'^T + bo + x  (M=512,N=1024,K=512), flag-dtype store
        mfma_gemm<true><<<dim3(8, 4, NBATCH), blk, 0, stream>>>(
            Wob, O, d_out, 512, 512, 512, 1024, 0L, CHW, CHW, 0,
            bO, FNUL, 1.f, x, CHW, flag);
    } else {
        // tier 3: fully per-batch (ws >= 9 MB)
        bf16* xn = (bf16*)(ws + 3 * MB);      // 1 MB
        bf16* V  = (bf16*)(ws + 4 * MB);      // 1 MB
        bf16* QK = (bf16*)(ws + 5 * MB);      // 2 MB
        bf16* S  = (bf16*)(ws + 7 * MB);      // 2 MB
        bf16* O  = xn;
        for (int b = 0; b < NBATCH; ++b) {
            gn_apply_kernel<<<dim3(16, 8, 1), blk, 0, stream>>>(
                x, flag, stats, gamma, beta, xn, b);
            mfma_gemm<false><<<dim3(8, 8, 1), blk, 0, stream>>>(
                xn, Wqk, QK, 512, 512, 512, 1024, 0L, 0L, 0L, 0,
                FNUL, bQK, 1.f, VNUL, 0L, nullptr);
            mfma_gemm<false><<<dim3(8, 4, 1), blk, 0, stream>>>(
                Wvb, xn, V, 512, 512, 512, 1024, 0L, 0L, 0L, 0,
                bV, FNUL, 1.f, VNUL, 0L, nullptr);
            mfma_gemm<false><<<dim3(8, 8, 1), blk, 0, stream>>>(
                QK, QK + 512, S, 512, 1024, 1024, 1024, 0L, 0L, 0L, 0,
                FNUL, FNUL, scale, VNUL, 0L, nullptr);
            softmax_kernel<<<dim3(HWN), blk, 0, stream>>>(S);
            mfma_gemm<false><<<dim3(4, 8, 1), blk, 0, stream>>>(
                S, V, O, 1024, 1024, 1024, 512, 0L, 0L, 0L, 0,
                FNUL, FNUL, 1.f, VNUL, 0L, nullptr);
            mfma_gemm<true><<<dim3(8, 4, 1), blk, 0, stream>>>(
                Wob, O, d_out, 512, 512, 512, 1024, 0L, 0L, CHW, b,
                bO, FNUL, 1.f, x, CHW, flag);
        }
    }
}

// Round 8
// 292.724 us; speedup vs baseline: 1.9326x; 1.5526x over previous
//
#include <hip/hip_runtime.h>
#include <hip/hip_bf16.h>

#define HWN    1024
#define CCH    512
#define NBATCH 16
#define NGROUP 32
#define EPSV   1e-5f

using bf16 = __hip_bfloat16;
typedef __attribute__((ext_vector_type(4))) float f32x4;
typedef __attribute__((ext_vector_type(8))) short s16x8;

// Runtime-dtyped element access: c==1 -> fp32, c==0 -> bf16 storage.
__device__ __forceinline__ float ldv(const void* p, long i, int c) {
    return c ? ((const float*)p)[i] : __bfloat162float(((const bf16*)p)[i]);
}
__device__ __forceinline__ void stv(void* p, long i, int c, float v) {
    if (c) ((float*)p)[i] = v;
    else   ((bf16*)p)[i]  = __float2bfloat16(v);
}

// async global->LDS, 16B per lane; lds dest = wave-uniform base + lane*16
__device__ __forceinline__ void glds16(const void* g, void* l) {
    __builtin_amdgcn_global_load_lds(
        (const __attribute__((address_space(1))) void*)g,
        (__attribute__((address_space(3))) void*)l, 16, 0, 0);
}

// ---------------------------------------------------------------------------
// Storage dtype detector (proven in R3). flag=1 => fp32 storage.
// ---------------------------------------------------------------------------
__global__ __launch_bounds__(256) void detect_kernel(const void* __restrict__ x,
                                                     int* __restrict__ flag)
{
    const int tid = threadIdx.x;
    const unsigned short* h = (const unsigned short*)x;
    int ok = 0;
    for (int i = tid; i < 4096; i += 256) {
        int e = (h[2 * i] >> 7) & 0xFF;
        if (e >= 100 && e <= 135) ok++;
    }
    __shared__ int red[256];
    red[tid] = ok; __syncthreads();
    for (int off = 128; off > 0; off >>= 1) {
        if (tid < off) red[tid] += red[tid + off];
        __syncthreads();
    }
    if (tid == 0) flag[0] = (red[0] < 2458) ? 1 : 0;
}

// ---------------------------------------------------------------------------
// GroupNorm stats: one block per (batch, group) -> (mean, rstd). f4-vectorized.
// ---------------------------------------------------------------------------
__global__ __launch_bounds__(256) void gn_stats_kernel(const void* __restrict__ x,
                                                       const int* __restrict__ flag,
                                                       float2* __restrict__ stats)
{
    const int f = flag[0];
    const int b = blockIdx.x >> 5, g = blockIdx.x & 31;
    const long base = ((long)b * CCH + (long)g * (CCH / NGROUP)) * HWN;
    const int tid = threadIdx.x;
    const int n = (CCH / NGROUP) * HWN;       // 16384
    float s = 0.f, ss = 0.f;
    if (f) {
        const float4* xp = (const float4*)((const float*)x + base);
        #pragma unroll
        for (int k = 0; k < 16; ++k) {
            float4 u = xp[tid + k * 256];
            s  += u.x + u.y + u.z + u.w;
            ss += u.x * u.x + u.y * u.y + u.z * u.z + u.w * u.w;
        }
    } else {
        for (int i = tid; i < n; i += 256) {
            float v = ldv(x, base + i, 0);
            s += v; ss += v * v;
        }
    }
    __shared__ float r1[256], r2[256];
    r1[tid] = s; r2[tid] = ss; __syncthreads();
    for (int off = 128; off > 0; off >>= 1) {
        if (tid < off) { r1[tid] += r1[tid + off]; r2[tid] += r2[tid + off]; }
        __syncthreads();
    }
    if (tid == 0) {
        float mean = r1[0] / n;
        float var  = r2[0] / n - mean * mean;
        stats[blockIdx.x] = make_float2(mean, rsqrtf(var + EPSV));
    }
}

// ---------------------------------------------------------------------------
// Weight/bias prep: Wqk = [Wq;Wk] bf16 [1024][512]; Wv,Wo bf16; biases f32.
// ---------------------------------------------------------------------------
__global__ __launch_bounds__(256)
void prep_kernel(const void* __restrict__ Wq, const void* __restrict__ Wk,
                 const void* __restrict__ Wv, const void* __restrict__ Wo,
                 const void* __restrict__ bq, const void* __restrict__ bk,
                 const void* __restrict__ bv, const void* __restrict__ bo,
                 const int* __restrict__ flag,
                 bf16* __restrict__ Wqk, bf16* __restrict__ Wvb, bf16* __restrict__ Wob,
                 float* __restrict__ bQK, float* __restrict__ bV, float* __restrict__ bO)
{
    const int f = flag[0];
    const int idx = blockIdx.x * 256 + threadIdx.x;
    if (idx < 524288) {
        const int r = idx >> 9, c = idx & 511;
        float v = (r < 512) ? ldv(Wq, (long)r * 512 + c, f)
                            : ldv(Wk, (long)(r - 512) * 512 + c, f);
        Wqk[idx] = __float2bfloat16(v);
    } else if (idx < 786432) {
        Wvb[idx - 524288] = __float2bfloat16(ldv(Wv, idx - 524288, f));
    } else if (idx < 1048576) {
        Wob[idx - 786432] = __float2bfloat16(ldv(Wo, idx - 786432, f));
    } else {
        const int j = idx - 1048576;
        if      (j < 512)  bQK[j]        = ldv(bq, j, f);
        else if (j < 1024) bQK[j]        = ldv(bk, j - 512, f);
        else if (j < 1536) bV[j - 1024]  = ldv(bv, j - 1024, f);
        else if (j < 2048) bO[j - 1536]  = ldv(bo, j - 1536, f);
    }
}

// ---------------------------------------------------------------------------
// GN+SiLU with transpose: x [c][i] (flag dtype) -> xn' [i][c] bf16.
// ---------------------------------------------------------------------------
__global__ __launch_bounds__(256)
void gn_apply_kernel(const void* __restrict__ x, const int* __restrict__ flag,
                     const float2* __restrict__ stats,
                     const void* __restrict__ gamma, const void* __restrict__ beta,
                     bf16* __restrict__ xn, int zb)
{
    const int f = flag[0];
    __shared__ float t[64][65];
    const int bz = blockIdx.z;
    const int bx = zb + bz;
    const int i0 = blockIdx.x * 64;
    const int c0 = blockIdx.y * 64;
    const int tid = threadIdx.x;
    const int il = tid & 63;
    const int hq = tid >> 6;              // 0..3
    #pragma unroll
    for (int r = 0; r < 16; ++r) {
        const int cl = r * 4 + hq;
        const int c = c0 + cl;
        const float2 st = stats[bx * NGROUP + (c >> 4)];
        const float ga = ldv(gamma, c, f), be = ldv(beta, c, f);
        float v = ldv(x, (long)bx * CCH * HWN + (long)c * HWN + i0 + il, f);
        v = (v - st.x) * st.y * ga + be;
        t[cl][il] = v / (1.f + __expf(-v));     // SiLU
    }
    __syncthreads();
    #pragma unroll
    for (int r = 0; r < 16; ++r) {
        const int ii = r * 4 + hq;
        xn[(long)bz * CCH * HWN + (long)(i0 + ii) * CCH + c0 + il] =
            __float2bfloat16(t[il][ii]);
    }
}

// ---------------------------------------------------------------------------
// MFMA TN GEMM (R5-proven core: glds16 double-buffer + XOR bank swizzle,
// 0 measured conflicts, VGPR 80): C[m][n] = alpha * sum_k A[m][k] * B[n][k]
// 128x128 tile, BK=32, 4 waves, 16x16x32 bf16.
// EXPS: epilogue stores exp(clamp(v)) and atomically accumulates row sums
//       into lsum[zA*1024+m]  (softmax numerator + denominator, no max-sub:
//       logits are O(10), fp32 exp safe; clamp 60 guards tails).
// RDIV: epilogue multiplies by 1/lsum[m]  (softmax completion inside PV).
// ---------------------------------------------------------------------------
template<bool FINAL, bool EXPS, bool RDIV>
__global__ __launch_bounds__(256)
void mfma_gemm(const bf16* __restrict__ A, const bf16* __restrict__ B,
               void* __restrict__ C, int K,
               int lda, int ldb, int ldc,
               long sA, long sB, long sC, int z0,
               const float* __restrict__ rowBias, const float* __restrict__ colBias,
               float alpha, const void* __restrict__ resid, long sR,
               const int* __restrict__ flag, float* __restrict__ lsum)
{
    __shared__ bf16 lA[2][128 * 32];
    __shared__ bf16 lB[2][128 * 32];

    const int tid = threadIdx.x;
    const int w   = tid >> 6;         // wave 0..3
    const int l   = tid & 63;
    const int ln  = l & 15;
    const int qd  = l >> 4;           // 0..3
    const int wm  = (w >> 1) * 64;
    const int wn  = (w & 1) * 64;
    const int zA  = z0 + blockIdx.z;

    const bf16* Ab = A + (long)zA * sA;
    const bf16* Bb = B + (long)zA * sB;
    const int m0 = blockIdx.y * 128;
    const int n0 = blockIdx.x * 128;

    // staging: lane -> local row l>>2, LDS slot l&3 which holds swizzled kseg
    const int sr   = l >> 2;
    const int kswz = ((l & 3) ^ ((l >> 3) & 3)) * 8;   // global col offset
    const bf16* gA0 = Ab + (long)(m0 + w * 16 + sr) * lda + kswz;
    const bf16* gA1 = gA0 + (long)64 * lda;
    const bf16* gB0 = Bb + (long)(n0 + w * 16 + sr) * ldb + kswz;
    const bf16* gB1 = gB0 + (long)64 * ldb;

    f32x4 acc[4][4];
    #pragma unroll
    for (int i = 0; i < 4; ++i)
        #pragma unroll
        for (int j = 0; j < 4; ++j)
            acc[i][j] = (f32x4){0.f, 0.f, 0.f, 0.f};

    // swizzled fragment read offsets; 2-way bank aliasing only (free, m136)
    const int swA = (qd ^ ((ln >> 1) & 3)) * 8;

    // prologue: stage tile 0 into buffer 0
    glds16(gA0, &lA[0][w * 512]);
    glds16(gA1, &lA[0][2048 + w * 512]);
    glds16(gB0, &lB[0][w * 512]);
    glds16(gB1, &lB[0][2048 + w * 512]);

    const int NK = K >> 5;
    for (int t = 0; t < NK; ++t) {
        const int p = t & 1;
        __syncthreads();               // tile t resident; prior reads done
        if (t + 1 < NK) {              // stage tile t+1 (overlaps MFMA below)
            const int kk = (t + 1) << 5;
            glds16(gA0 + kk, &lA[p ^ 1][w * 512]);
            glds16(gA1 + kk, &lA[p ^ 1][2048 + w * 512]);
            glds16(gB0 + kk, &lB[p ^ 1][w * 512]);
            glds16(gB1 + kk, &lB[p ^ 1][2048 + w * 512]);
        }
        s16x8 af[4], bfr[4];
        #pragma unroll
        for (int i = 0; i < 4; ++i)
            af[i] = *(const s16x8*)&lA[p][(wm + i * 16 + ln) * 32 + swA];
        #pragma unroll
        for (int j = 0; j < 4; ++j)
            bfr[j] = *(const s16x8*)&lB[p][(wn + j * 16 + ln) * 32 + swA];
        #pragma unroll
        for (int i = 0; i < 4; ++i)
            #pragma unroll
            for (int j = 0; j < 4; ++j)
                acc[i][j] = __builtin_amdgcn_mfma_f32_16x16x32_bf16(
                    af[i], bfr[j], acc[i][j], 0, 0, 0);
    }

    // epilogue: C/D layout col = lane&15, row = qd*4 + reg  [m89]
    const int f = (FINAL && flag) ? flag[0] : 0;
    #pragma unroll
    for (int i = 0; i < 4; ++i) {
        #pragma unroll
        for (int r = 0; r < 4; ++r) {
            const int m = m0 + wm + i * 16 + qd * 4 + r;
            const float rb = rowBias ? rowBias[m] : 0.f;
            const float inv = RDIV ? (1.f / lsum[(long)zA * HWN + m]) : 1.f;
            float sp = 0.f;
            #pragma unroll
            for (int j = 0; j < 4; ++j) {
                const int n = n0 + wn + j * 16 + ln;
                float v = alpha * acc[i][j][r] + rb;
                if (colBias) v += colBias[n];
                if (EXPS) { v = __expf(fminf(v, 60.f)); sp += v; }
                if (RDIV) v *= inv;
                const long idx = (long)zA * sC + (long)m * ldc + n;
                if (FINAL) {
                    if (resid) v += ldv(resid, (long)zA * sR + (long)m * ldc + n, f);
                    stv(C, idx, f, v);
                } else {
                    ((bf16*)C)[idx] = __float2bfloat16(v);
                }
            }
            if (EXPS) {
                #pragma unroll
                for (int o = 8; o > 0; o >>= 1) sp += __shfl_xor(sp, o);
                if (ln == 0) atomicAdd(&lsum[(long)zA * HWN + m], sp);
            }
        }
    }
}

// ---------------------------------------------------------------------------
extern "C" void kernel_launch(void* const* d_in, const int* in_sizes, int n_in,
                              void* d_out, int out_size, void* d_ws, size_t ws_size,
                              hipStream_t stream)
{
    // input order (insertion per docs; alphabetical fallback) — proven in R3
    const long NX = (long)NBATCH * CCH * HWN;
    int ix, iWq, ibq, iWk, ibk, iWv, ibv, iWo, ibo, iga, ibe;
    if (in_sizes[0] == NX) {
        ix = 0; iWq = 1; ibq = 2; iWk = 3; ibk = 4; iWv = 5; ibv = 6;
        iWo = 7; ibo = 8; iga = 9; ibe = 10;
    } else {
        iWk = 0; iWo = 1; iWq = 2; iWv = 3; ibe = 4; ibk = 5; ibo = 6;
        ibq = 7; ibv = 8; iga = 9; ix = 10;
    }
    const void* x     = d_in[ix];
    const void* Wq    = d_in[iWq];
    const void* bq    = d_in[ibq];
    const void* Wk    = d_in[iWk];
    const void* bk    = d_in[ibk];
    const void* Wv    = d_in[iWv];
    const void* bv    = d_in[ibv];
    const void* Wo    = d_in[iWo];
    const void* bo    = d_in[ibo];
    const void* gamma = d_in[iga];
    const void* beta  = d_in[ibe];

    const long CHW = (long)CCH * HWN;      // 524288
    const long NN  = (long)HWN * HWN;      // 1048576
    const size_t MB = 1ull << 20;
    char* ws = (char*)d_ws;

    bf16*   Wqk   = (bf16*)ws;                         // 1 MB
    bf16*   Wvb   = (bf16*)(ws + MB);                  // 0.5 MB
    bf16*   Wob   = (bf16*)(ws + MB + MB / 2);         // 0.5 MB
    float*  bQK   = (float*)(ws + 2 * MB);
    float*  bV    = (float*)(ws + 2 * MB + 4096);
    float*  bO    = (float*)(ws + 2 * MB + 6144);
    float2* stats = (float2*)(ws + 2 * MB + 8192);     // 4 KB
    int*    flag  = (int*)(ws + 2 * MB + 12288);
    float*  lsum  = (float*)(ws + 2 * MB + 16384);     // 64 KB row sums

    dim3 blk(256);
    const float scale = 0.044194173824159216f;   // 512^-0.5
    const float* FNUL = nullptr;
    const void*  VNUL = nullptr;
    float* LNUL = nullptr;

    detect_kernel<<<dim3(1), blk, 0, stream>>>(x, flag);
    gn_stats_kernel<<<dim3(NBATCH * NGROUP), blk, 0, stream>>>(x, flag, stats);
    prep_kernel<<<dim3(4104), blk, 0, stream>>>(Wq, Wk, Wv, Wo, bq, bk, bv, bo,
                                                flag, Wqk, Wvb, Wob, bQK, bV, bO);
    hipMemsetAsync(lsum, 0, (size_t)NBATCH * HWN * sizeof(float), stream);

    const int tier = (ws_size >= 100 * MB) ? 1 : (ws_size >= 70 * MB) ? 2 : 3;

    if (tier <= 2) {
        bf16* xn = (bf16*)(ws + 3 * MB);      // 16 MB [i][c] per batch
        bf16* V  = (bf16*)(ws + 19 * MB);     // 16 MB [c][j] per batch
        bf16* QK = (bf16*)(ws + 35 * MB);     // 32 MB [i][1024] per batch
        bf16* S  = (bf16*)(ws + 67 * MB);     // 32 MB (tier1) / 2 MB (tier2)
        bf16* O  = xn;                        // overlay: xn dead after V GEMM

        gn_apply_kernel<<<dim3(16, 8, NBATCH), blk, 0, stream>>>(
            x, flag, stats, gamma, beta, xn, 0);

        // QK' = xn' @ [Wq;Wk]^T + bias  (M=1024,N=1024,K=512)
        mfma_gemm<false, false, false><<<dim3(8, 8, NBATCH), blk, 0, stream>>>(
            xn, Wqk, QK, 512, 512, 512, 1024, CHW, 0L, NN, 0,
            FNUL, bQK, 1.f, VNUL, 0L, nullptr, LNUL);
        // V[c][j] = Wv @ gn(x): A=Wv, B=xn'  (M=512,N=1024,K=512)
        mfma_gemm<false, false, false><<<dim3(8, 4, NBATCH), blk, 0, stream>>>(
            Wvb, xn, V, 512, 512, 512, 1024, 0L, CHW, CHW, 0,
            bV, FNUL, 1.f, VNUL, 0L, nullptr, LNUL);

        if (tier == 1) {
            // S~ = exp(scale * Q' K'^T), row sums -> lsum (M=N=1024,K=512)
            mfma_gemm<false, true, false><<<dim3(8, 8, NBATCH), blk, 0, stream>>>(
                QK, QK + 512, S, 512, 1024, 1024, 1024, NN, NN, NN, 0,
                FNUL, FNUL, scale, VNUL, 0L, nullptr, lsum);
            // O' = (S~ @ V^T) / l  (M=1024,N=512,K=1024)
            mfma_gemm<false, false, true><<<dim3(4, 8, NBATCH), blk, 0, stream>>>(
                S, V, O, 1024, 1024, 1024, 512, NN, CHW, CHW, 0,
                FNUL, FNUL, 1.f, VNUL, 0L, nullptr, lsum);
        } else {
            for (int b = 0; b < NBATCH; ++b) {
                mfma_gemm<false, true, false><<<dim3(8, 8, 1), blk, 0, stream>>>(
                    QK, QK + 512, S, 512, 1024, 1024, 1024, NN, NN, 0L, b,
                    FNUL, FNUL, scale, VNUL, 0L, nullptr, lsum);
                mfma_gemm<false, false, true><<<dim3(4, 8, 1), blk, 0, stream>>>(
                    S, V, O, 1024, 1024, 1024, 512, 0L, CHW, CHW, b,
                    FNUL, FNUL, 1.f, VNUL, 0L, nullptr, lsum);
            }
        }
        // out = Wo @ O'^T + bo + x  (M=512,N=1024,K=512), flag-dtype store
        mfma_gemm<true, false, false><<<dim3(8, 4, NBATCH), blk, 0, stream>>>(
            Wob, O, d_out, 512, 512, 512, 1024, 0L, CHW, CHW, 0,
            bO, FNUL, 1.f, x, CHW, flag, LNUL);
    } else {
        // tier 3: fully per-batch (ws >= 9 MB)
        bf16* xn = (bf16*)(ws + 3 * MB);      // 1 MB
        bf16* V  = (bf16*)(ws + 4 * MB);      // 1 MB
        bf16* QK = (bf16*)(ws + 5 * MB);      // 2 MB
        bf16* S  = (bf16*)(ws + 7 * MB);      // 2 MB
        bf16* O  = xn;
        for (int b = 0; b < NBATCH; ++b) {
            gn_apply_kernel<<<dim3(16, 8, 1), blk, 0, stream>>>(
                x, flag, stats, gamma, beta, xn, b);
            mfma_gemm<false, false, false><<<dim3(8, 8, 1), blk, 0, stream>>>(
                xn, Wqk, QK, 512, 512, 512, 1024, 0L, 0L, 0L, 0,
                FNUL, bQK, 1.f, VNUL, 0L, nullptr, LNUL);
            mfma_gemm<false, false, false><<<dim3(8, 4, 1), blk, 0, stream>>>(
                Wvb, xn, V, 512, 512, 512, 1024, 0L, 0L, 0L, 0,
                bV, FNUL, 1.f, VNUL, 0L, nullptr, LNUL);
            mfma_gemm<false, true, false><<<dim3(8, 8, 1), blk, 0, stream>>>(
                QK, QK + 512, S, 512, 1024, 1024, 1024, 0L, 0L, 0L, b,
                FNUL, FNUL, scale, VNUL, 0L, nullptr, lsum);
            mfma_gemm<false, false, true><<<dim3(4, 8, 1), blk, 0, stream>>>(
                S, V, O, 1024, 1024, 1024, 512, 0L, 0L, 0L, b,
                FNUL, FNUL, 1.f, VNUL, 0L, nullptr, lsum);
            mfma_gemm<true, false, false><<<dim3(8, 4, 1), blk, 0, stream>>>(
                Wob, O, d_out, 512, 512, 512, 1024, 0L, 0L, CHW, b,
                bO, FNUL, 1.f, x, CHW, flag, LNUL);
        }
    }
}